// Round 5
// baseline (115.218 us; speedup 1.0000x reference)
//
#include <hip/hip_runtime.h>

// VA forward: out[row, 3j:3j+3] = M(theta_row) @ ((p + t) * (p != 0))
// where M = Rz(th2) * Ry(th0) * Rx(th1), t = th[3:6].
//
// 5 joints (15 floats, 60B) per thread: 25 joints/row = 5 threads/row
// exactly -> no row crossing, trig ONCE per thread. Vector NT loads/stores
// (x4,x4,x4,x2,x1) cut memory-instruction count 3x vs scalar NT.
// 614400 rows * 5 = 3.072M threads = 12000 blocks of 256 exact.

typedef float f32x4 __attribute__((ext_vector_type(4), aligned(4)));
typedef float f32x2 __attribute__((ext_vector_type(2), aligned(4)));

constexpr int BLOCK = 256;

__global__ __launch_bounds__(BLOCK) void va_kernel(
    const float* __restrict__ conv,
    const float* __restrict__ theta,
    float* __restrict__ out)
{
    int idx = blockIdx.x * BLOCK + threadIdx.x;

    unsigned row  = (unsigned)idx / 5u;          // magic-mul div
    unsigned part = (unsigned)idx - row * 5u;
    size_t base = (size_t)row * 75 + part * 15;

    // ---- load 15 floats as x4,x4,x4,x2,x1 (non-temporal) ----
    const float* p = conv + base;
    f32x4 A = __builtin_nontemporal_load((const f32x4*)(p + 0));
    f32x4 Bv = __builtin_nontemporal_load((const f32x4*)(p + 4));
    f32x4 Cv = __builtin_nontemporal_load((const f32x4*)(p + 8));
    f32x2 D = __builtin_nontemporal_load((const f32x2*)(p + 12));
    float E = __builtin_nontemporal_load(p + 14);

    float v[15] = {A.x, A.y, A.z, A.w,
                   Bv.x, Bv.y, Bv.z, Bv.w,
                   Cv.x, Cv.y, Cv.z, Cv.w,
                   D.x, D.y, E};

    // ---- theta (cached; 5 threads share a row -> L1 broadcast) ----
    const float* th = theta + (size_t)row * 6;
    float ay = th[0], ax = th[1], az = th[2];
    float tx = th[3], ty = th[4], tz = th[5];

    float sy = __sinf(ay), cy = __cosf(ay);
    float sx = __sinf(ax), cx = __cosf(ax);
    float sz = __sinf(az), cz = __cosf(az);

    // M = Rz(az) * Ry(ay) * Rx(ax)
    float m00 = cz * cy;
    float m01 = -sz * cx + cz * sy * sx;
    float m02 =  sz * sx + cz * sy * cx;
    float m10 = sz * cy;
    float m11 =  cz * cx + sz * sy * sx;
    float m12 = -cz * sx + sz * sy * cx;
    float m20 = -sy;
    float m21 = cy * sx;
    float m22 = cy * cx;

    float w[15];
    #pragma unroll
    for (int j = 0; j < 5; ++j) {
        float x = v[3 * j + 0];
        float y = v[3 * j + 1];
        float z = v[3 * j + 2];

        float qx = (x != 0.0f) ? (x + tx) : 0.0f;
        float qy = (y != 0.0f) ? (y + ty) : 0.0f;
        float qz = (z != 0.0f) ? (z + tz) : 0.0f;

        w[3 * j + 0] = m00 * qx + m01 * qy + m02 * qz;
        w[3 * j + 1] = m10 * qx + m11 * qy + m12 * qz;
        w[3 * j + 2] = m20 * qx + m21 * qy + m22 * qz;
    }

    // ---- store 15 floats as x4,x4,x4,x2,x1 (non-temporal) ----
    float* o = out + base;
    f32x4 oA = {w[0], w[1], w[2], w[3]};
    f32x4 oB = {w[4], w[5], w[6], w[7]};
    f32x4 oC = {w[8], w[9], w[10], w[11]};
    f32x2 oD = {w[12], w[13]};
    __builtin_nontemporal_store(oA, (f32x4*)(o + 0));
    __builtin_nontemporal_store(oB, (f32x4*)(o + 4));
    __builtin_nontemporal_store(oC, (f32x4*)(o + 8));
    __builtin_nontemporal_store(oD, (f32x2*)(o + 12));
    __builtin_nontemporal_store(w[14], o + 14);
}

extern "C" void kernel_launch(void* const* d_in, const int* in_sizes, int n_in,
                              void* d_out, int out_size, void* d_ws, size_t ws_size,
                              hipStream_t stream) {
    const float* conv  = (const float*)d_in[0];
    const float* theta = (const float*)d_in[1];
    float* out = (float*)d_out;

    int nrows   = out_size / 75;                  // 614400
    int threads = nrows * 5;                      // 3.072M
    int blocks  = threads / BLOCK;                // 12000 exact
    va_kernel<<<blocks, BLOCK, 0, stream>>>(conv, theta, out);
}

// Round 6
// 96.648 us; speedup vs baseline: 1.1921x; 1.1921x over previous
//
#include <hip/hip_runtime.h>

// VA forward: out[row, 3j:3j+3] = M(theta_row) @ ((p + t) * (p != 0)),
// M = Rz(th2)*Ry(th0)*Rx(th1), t = th[3:6].
//
// Dense-float4 structure: thread q owns floats [4q, 4q+4) of the flat
// 46.08M-float tensor. Every global load/store instruction is 64 lanes x
// 16B contiguous = 1KiB, full-cacheline NT (fixes R5's partial-line RMW
// amplification and R4's stride-12 partial coverage). Joint (3-float)
// alignment is recovered in-register: 2 neighbor floats on each side via
// __shfl; wave-edge lanes re-load 2 scalars (cached, L2-hit). Each of the
// 4 components picks its row's matrix (<=2 rows straddle a float4; both
// built unconditionally - trig is negligible). All selects are unrolled
// cndmasks; no dynamic register indexing.

typedef float f32x4 __attribute__((ext_vector_type(4)));

constexpr int BLOCK = 256;

__global__ __launch_bounds__(BLOCK) void va_kernel(
    const float* __restrict__ conv,
    const float* __restrict__ theta,
    float* __restrict__ out,
    int F)                       // total floats = 46,080,000 (75 | F)
{
    int q = blockIdx.x * BLOCK + threadIdx.x;   // float4 index
    int g = q << 2;                             // flat float index

    f32x4 A = __builtin_nontemporal_load((const f32x4*)conv + q);

    int lane = threadIdx.x & 63;

    // window w0..w7 = floats [g-2, g+6)
    float w0 = __shfl_up(A.z, 1);
    float w1 = __shfl_up(A.w, 1);
    float w6 = __shfl_down(A.x, 1);
    float w7 = __shfl_down(A.y, 1);
    if (lane == 0) {
        w0 = (g >= 2) ? conv[g - 2] : 0.0f;
        w1 = (g >= 1) ? conv[g - 1] : 0.0f;
    }
    if (lane == 63) {
        w6 = (g + 4 < F) ? conv[g + 4] : 0.0f;
        w7 = (g + 5 < F) ? conv[g + 5] : 0.0f;
    }
    float w2 = A.x, w3 = A.y, w4 = A.z, w5 = A.w;

    unsigned ug = (unsigned)g;
    unsigned ra = ug / 75u;            // magic-mul
    unsigned u0 = ug - ra * 75u;       // 0..74
    unsigned rb = (u0 >= 72u) ? ra + 1u : ra;   // row of any straddling comp

    float a00,a01,a02,a10,a11,a12,a20,a21,a22, atx,aty,atz;
    float b00,b01,b02,b10,b11,b12,b20,b21,b22, btx,bty,btz;
    {
        const float* th = theta + (size_t)ra * 6;
        float ay=th[0], ax=th[1], az=th[2]; atx=th[3]; aty=th[4]; atz=th[5];
        float sy=__sinf(ay), cy=__cosf(ay);
        float sx=__sinf(ax), cx=__cosf(ax);
        float sz=__sinf(az), cz=__cosf(az);
        a00=cz*cy; a01=-sz*cx+cz*sy*sx; a02= sz*sx+cz*sy*cx;
        a10=sz*cy; a11= cz*cx+sz*sy*sx; a12=-cz*sx+sz*sy*cx;
        a20=-sy;   a21=cy*sx;           a22=cy*cx;
    }
    {
        const float* th = theta + (size_t)rb * 6;
        float ay=th[0], ax=th[1], az=th[2]; btx=th[3]; bty=th[4]; btz=th[5];
        float sy=__sinf(ay), cy=__cosf(ay);
        float sx=__sinf(ax), cx=__cosf(ax);
        float sz=__sinf(az), cz=__cosf(az);
        b00=cz*cy; b01=-sz*cx+cz*sy*sx; b02= sz*sx+cz*sy*cx;
        b10=sz*cy; b11= cz*cx+sz*sy*sx; b12=-cz*sx+sz*sy*cx;
        b20=-sy;   b21=cy*sx;           b22=cy*cx;
    }

    f32x4 O;

    // Component i (i compile-time): window elems v0..v4 = w[i..i+4].
    // c = (u0+i) % 3 within its row; joint floats sit at window idx
    // (i+2-c, i+3-c, i+4-c).
#define COMP(i, v0, v1, v2, v3, v4, OUT)                                   \
    {                                                                      \
        unsigned ui  = u0 + (i);                                           \
        bool     inB = ui >= 75u;                                          \
        unsigned uu  = inB ? ui - 75u : ui;                                \
        unsigned c   = uu - (uu / 3u) * 3u;                                \
        float s0 = (c == 0u) ? (v2) : ((c == 1u) ? (v1) : (v0));           \
        float s1 = (c == 0u) ? (v3) : ((c == 1u) ? (v2) : (v1));           \
        float s2 = (c == 0u) ? (v4) : ((c == 1u) ? (v3) : (v2));           \
        float tx = inB ? btx : atx;                                        \
        float ty = inB ? bty : aty;                                        \
        float tz = inB ? btz : atz;                                        \
        float qx = (s0 != 0.0f) ? s0 + tx : 0.0f;                          \
        float qy = (s1 != 0.0f) ? s1 + ty : 0.0f;                          \
        float qz = (s2 != 0.0f) ? s2 + tz : 0.0f;                          \
        float p0 = (c == 0u) ? a00 : ((c == 1u) ? a10 : a20);              \
        float p1 = (c == 0u) ? a01 : ((c == 1u) ? a11 : a21);              \
        float p2 = (c == 0u) ? a02 : ((c == 1u) ? a12 : a22);              \
        float r0 = (c == 0u) ? b00 : ((c == 1u) ? b10 : b20);              \
        float r1 = (c == 0u) ? b01 : ((c == 1u) ? b11 : b21);              \
        float r2 = (c == 0u) ? b02 : ((c == 1u) ? b12 : b22);              \
        float m0 = inB ? r0 : p0;                                          \
        float m1 = inB ? r1 : p1;                                          \
        float m2 = inB ? r2 : p2;                                          \
        OUT = m0 * qx + m1 * qy + m2 * qz;                                 \
    }

    COMP(0, w0, w1, w2, w3, w4, O.x)
    COMP(1, w1, w2, w3, w4, w5, O.y)
    COMP(2, w2, w3, w4, w5, w6, O.z)
    COMP(3, w3, w4, w5, w6, w7, O.w)
#undef COMP

    __builtin_nontemporal_store(O, (f32x4*)out + q);
}

extern "C" void kernel_launch(void* const* d_in, const int* in_sizes, int n_in,
                              void* d_out, int out_size, void* d_ws, size_t ws_size,
                              hipStream_t stream) {
    const float* conv  = (const float*)d_in[0];
    const float* theta = (const float*)d_in[1];
    float* out = (float*)d_out;

    int F = out_size;                     // 46,080,000 floats
    int nf4 = F / 4;                      // 11,520,000
    int blocks = nf4 / BLOCK;             // 45,000 exact
    va_kernel<<<blocks, BLOCK, 0, stream>>>(conv, theta, out, F);
}

// Round 7
// 64.886 us; speedup vs baseline: 1.7757x; 1.4895x over previous
//
#include <hip/hip_runtime.h>

// VA forward: out[row, 3j:3j+3] = M(theta_row) @ ((p + t) * (p != 0))
// where M = Rz(th2) * Ry(th0) * Rx(th1), t = th[3:6].
// One thread per joint (R4 structure, best = 67.9us).
// This round's isolated change: NT on LOADS only (read-once stream, don't
// pollute L2); stores are CACHED so L2 write-combines the stride-12 scalar
// stores into full 64B lines (R5's counters showed NT partial-line stores
// amplify WRITE_SIZE by ~40%).

constexpr int JOINTS = 25;

__global__ __launch_bounds__(256) void va_kernel(
    const float* __restrict__ conv,
    const float* __restrict__ theta,
    float* __restrict__ out,
    int total)   // total = N * JOINTS joint-tasks
{
    int idx = blockIdx.x * 256 + threadIdx.x;
    if (idx >= total) return;

    unsigned row = (unsigned)idx / JOINTS;        // magic-mul div by 25
    unsigned j   = (unsigned)idx - row * JOINTS;

    const float* th = theta + (size_t)row * 6;
    float ay = th[0], ax = th[1], az = th[2];
    float tx = th[3], ty = th[4], tz = th[5];

    float sy = __sinf(ay), cy = __cosf(ay);
    float sx = __sinf(ax), cx = __cosf(ax);
    float sz = __sinf(az), cz = __cosf(az);

    // M = Rz(az) * Ry(ay) * Rx(ax)
    float m00 = cz * cy;
    float m01 = -sz * cx + cz * sy * sx;
    float m02 =  sz * sx + cz * sy * cx;
    float m10 = sz * cy;
    float m11 =  cz * cx + sz * sy * sx;
    float m12 = -cz * sx + sz * sy * cx;
    float m20 = -sy;
    float m21 = cy * sx;
    float m22 = cy * cx;

    const float* p = conv + (size_t)row * 75 + j * 3;
    float x = __builtin_nontemporal_load(p + 0);
    float y = __builtin_nontemporal_load(p + 1);
    float z = __builtin_nontemporal_load(p + 2);

    float qx = (x != 0.0f) ? (x + tx) : 0.0f;
    float qy = (y != 0.0f) ? (y + ty) : 0.0f;
    float qz = (z != 0.0f) ? (z + tz) : 0.0f;

    float ox = m00 * qx + m01 * qy + m02 * qz;
    float oy = m10 * qx + m11 * qy + m12 * qz;
    float oz = m20 * qx + m21 * qy + m22 * qz;

    float* o = out + (size_t)row * 75 + j * 3;
    o[0] = ox;   // cached stores: L2 write-combines stride-12 scalars
    o[1] = oy;
    o[2] = oz;
}

extern "C" void kernel_launch(void* const* d_in, const int* in_sizes, int n_in,
                              void* d_out, int out_size, void* d_ws, size_t ws_size,
                              hipStream_t stream) {
    const float* conv  = (const float*)d_in[0];
    const float* theta = (const float*)d_in[1];
    float* out = (float*)d_out;

    int total = out_size / 3;                 // N * 25 joint tasks
    int blocks = (total + 255) / 256;
    va_kernel<<<blocks, 256, 0, stream>>>(conv, theta, out, total);
}